// Round 1
// baseline (9223.561 us; speedup 1.0000x reference)
//
#include <hip/hip_runtime.h>
#include <math.h>

// ---------------------------------------------------------------------------
// ACARHead: fp32 baseline implementation.
// Shapes: N=64 ROIs, C_R=1024, HID=512, H,W=16->14->7, DEPTH=2, NCLS=60.
// conv1 (1x1 on concat(bg,actor)) is decomposed into A[o,p] (bg part, shared
// over n) + B[n,o] (actor part) and fused into conv2's input staging.
// ---------------------------------------------------------------------------

#define NROI 64
#define CR   1024
#define HIDC 512
#define NCLS 60

// ---------- conv1 decomposition ----------
// A[o,p] = sum_c w1[o,c] * bg[c,p]   (o<512, p<256, c<1024)
__global__ __launch_bounds__(256) void k_Apart(
    const float* __restrict__ w1, const float* __restrict__ bg,
    float* __restrict__ A)
{
    const int o = blockIdx.x;      // 512
    const int p = threadIdx.x;     // 256
    const float* wr = w1 + o * (2 * CR);
    float acc = 0.f;
    for (int c = 0; c < CR; ++c)
        acc = fmaf(wr[c], bg[c * 256 + p], acc);
    A[o * 256 + p] = acc;
}

// B[n,o] = sum_c w1[o,1024+c] * actor[n,c]
__global__ __launch_bounds__(512) void k_Bpart(
    const float* __restrict__ w1, const float* __restrict__ actor,
    float* __restrict__ B)
{
    const int n = blockIdx.x;      // 64
    const int o = threadIdx.x;     // 512
    const float* ar = actor + n * CR;
    const float* wr = w1 + o * (2 * CR) + CR;
    float acc = 0.f;
    for (int c = 0; c < CR; ++c)
        acc = fmaf(ar[c], wr[c], acc);
    B[n * HIDC + o] = acc;
}

// ---------- conv2: 3x3 valid, 16x16 -> 14x14, relu; input built on the fly
// from A,B (x1[n,c,p] = relu(A[c,p] + B[n,c])) ----------
__global__ __launch_bounds__(256) void k_conv16to14(
    const float* __restrict__ A, const float* __restrict__ B,
    const float* __restrict__ w,   // [512,512,9]
    float* __restrict__ out)       // [64,512,196]
{
    const int n   = blockIdx.x;        // 64
    const int oc0 = blockIdx.y * 16;   // 32 tiles
    const int tid = threadIdx.x;
    const int oh = tid / 14, ow = tid % 14;
    const bool act = tid < 196;
    __shared__ float s_in[4 * 256];
    float acc[16];
#pragma unroll
    for (int q = 0; q < 16; ++q) acc[q] = 0.f;
    const float* Bn = B + n * HIDC;

    for (int c0 = 0; c0 < HIDC; c0 += 4) {
        __syncthreads();
#pragma unroll
        for (int cc = 0; cc < 4; ++cc)
            s_in[cc * 256 + tid] = fmaxf(A[(c0 + cc) * 256 + tid] + Bn[c0 + cc], 0.f);
        __syncthreads();
#pragma unroll 1
        for (int cc = 0; cc < 4; ++cc) {
            float tap[9];
#pragma unroll
            for (int kh = 0; kh < 3; ++kh)
#pragma unroll
                for (int kw = 0; kw < 3; ++kw)
                    tap[kh * 3 + kw] = s_in[cc * 256 + (oh + kh) * 16 + (ow + kw)];
            const int c = c0 + cc;
            const float* wp = w + (oc0 * HIDC + c) * 9;
#pragma unroll
            for (int q = 0; q < 16; ++q)
#pragma unroll
                for (int t = 0; t < 9; ++t)
                    acc[q] = fmaf(tap[t], wp[q * HIDC * 9 + t], acc[q]);
        }
    }
    if (act) {
        float* op = out + (n * HIDC + oc0) * 196 + tid;
#pragma unroll
        for (int q = 0; q < 16; ++q)
            op[q * 196] = fmaxf(acc[q], 0.f);
    }
}

// ---------- maxpool 3x3 stride 2 pad 1: 14x14 -> 7x7 ----------
__global__ __launch_bounds__(256) void k_pool(
    const float* __restrict__ in, float* __restrict__ out)
{
    const int idx = blockIdx.x * 256 + threadIdx.x;   // 64*512*49
    if (idx >= NROI * HIDC * 49) return;
    const int j = idx % 7, i = (idx / 7) % 7, nc = idx / 49;
    const float* ip = in + nc * 196;
    float mx = -INFINITY;
#pragma unroll
    for (int di = 0; di < 3; ++di) {
        const int r = 2 * i + di - 1;
        if (r < 0 || r >= 14) continue;
#pragma unroll
        for (int dj = 0; dj < 3; ++dj) {
            const int cj = 2 * j + dj - 1;
            if (cj < 0 || cj >= 14) continue;
            mx = fmaxf(mx, ip[r * 14 + cj]);
        }
    }
    out[idx] = mx;
}

// ---------- generic 3x3 pad=1 conv on 7x7, optional residual ----------
__global__ __launch_bounds__(256) void k_conv7(
    const float* __restrict__ in,    // [64,512,49]
    const float* __restrict__ w,     // [512,512,9]
    const float* __restrict__ resid, // nullable
    float* __restrict__ out)         // [64,512,49]
{
    const int n   = blockIdx.x;
    const int oc0 = blockIdx.y * 64;           // 8 tiles of 64 oc
    const int tid = threadIdx.x;
    const int jj  = __builtin_amdgcn_readfirstlane(tid >> 6);  // wave id 0..3
    const int m   = tid & 63;
    const int oh = m / 7, ow = m % 7;
    const bool act = m < 49;
    __shared__ float s_in[8 * 49];
    float acc[16];
#pragma unroll
    for (int q = 0; q < 16; ++q) acc[q] = 0.f;
    const float* inN = in + n * HIDC * 49;

    for (int c0 = 0; c0 < HIDC; c0 += 8) {
        __syncthreads();
        for (int idx = tid; idx < 8 * 49; idx += 256)
            s_in[idx] = inN[c0 * 49 + idx];
        __syncthreads();
#pragma unroll 1
        for (int cc = 0; cc < 8; ++cc) {
            float tap[9];
#pragma unroll
            for (int kh = 0; kh < 3; ++kh) {
                const int ih = oh + kh - 1;
#pragma unroll
                for (int kw = 0; kw < 3; ++kw) {
                    const int iw = ow + kw - 1;
                    const bool v = act && ih >= 0 && ih < 7 && iw >= 0 && iw < 7;
                    tap[kh * 3 + kw] = v ? s_in[cc * 49 + ih * 7 + iw] : 0.f;
                }
            }
            const int c = c0 + cc;
            const float* wp = w + ((oc0 + jj * 16) * HIDC + c) * 9;
#pragma unroll
            for (int q = 0; q < 16; ++q)
#pragma unroll
                for (int t = 0; t < 9; ++t)
                    acc[q] = fmaf(tap[t], wp[q * HIDC * 9 + t], acc[q]);
        }
    }
    if (act) {
        const int base = (n * HIDC + oc0 + jj * 16) * 49 + m;
        float* op = out + base;
        if (resid) {
            const float* rp = resid + base;
#pragma unroll
            for (int q = 0; q < 16; ++q)
                op[q * 49] = acc[q] + rp[q * 49];
        } else {
#pragma unroll
            for (int q = 0; q < 16; ++q)
                op[q * 49] = acc[q];
        }
    }
}

// ---------- transpose [r,c,p] -> [p,r,c] ----------
__global__ __launch_bounds__(256) void k_transpose(
    const float* __restrict__ src, float* __restrict__ dst)
{
    const int idx = blockIdx.x * 256 + threadIdx.x;   // 64*512*49
    if (idx >= NROI * HIDC * 49) return;
    const int c = idx % HIDC;
    const int r = (idx / HIDC) % NROI;
    const int p = idx / (HIDC * NROI);
    dst[idx] = src[(r * HIDC + c) * 49 + p];
}

// ---------- attention scores + softmax over m: att[n,p,m] ----------
__global__ __launch_bounds__(64) void k_att(
    const float* __restrict__ qT,   // [p,n,c]
    const float* __restrict__ kT,   // [p,m,c]
    float* __restrict__ att)        // [n,p,m]
{
    const int n = blockIdx.x;   // 64
    const int p = blockIdx.y;   // 49
    const int m = threadIdx.x;  // 64
    __shared__ float s_q[HIDC];
    const float* qrow = qT + (p * NROI + n) * HIDC;
    for (int c = m; c < HIDC; c += 64) s_q[c] = qrow[c];
    __syncthreads();
    const float* krow = kT + (p * NROI + m) * HIDC;
    float acc = 0.f;
    for (int c = 0; c < HIDC; ++c)
        acc = fmaf(s_q[c], krow[c], acc);
    acc *= 0.044194173824159216f;   // 1/sqrt(512)
    float mx = acc;
#pragma unroll
    for (int off = 32; off; off >>= 1) mx = fmaxf(mx, __shfl_xor(mx, off));
    const float e = expf(acc - mx);
    float s = e;
#pragma unroll
    for (int off = 32; off; off >>= 1) s += __shfl_xor(s, off);
    att[(n * 49 + p) * 64 + m] = e / s;
}

// ---------- virt[n,c,p] = sum_m att[n,p,m] * v[m,c,p] (vT is [p,m,c]) ------
__global__ __launch_bounds__(256) void k_virt(
    const float* __restrict__ att, const float* __restrict__ vT,
    float* __restrict__ virt)
{
    const int n = blockIdx.x, p = blockIdx.y;
    const int tid = threadIdx.x;
    __shared__ float s_a[64];
    if (tid < 64) s_a[tid] = att[(n * 49 + p) * 64 + tid];
    __syncthreads();
    const float* vp = vT + p * NROI * HIDC;
#pragma unroll
    for (int k = 0; k < 2; ++k) {
        const int c = tid + k * 256;
        float acc = 0.f;
        for (int m = 0; m < 64; ++m)
            acc = fmaf(s_a[m], vp[m * HIDC + c], acc);
        virt[(n * HIDC + c) * 49 + p] = acc;
    }
}

// ---------- GroupNorm(1,C) + relu, in-place over [n][512*49] ----------
__global__ __launch_bounds__(256) void k_gn_relu(
    float* __restrict__ x, const float* __restrict__ gamma,
    const float* __restrict__ beta)
{
    const int n = blockIdx.x;
    float* xp = x + n * HIDC * 49;
    const int cnt = HIDC * 49;   // 25088
    float s = 0.f, sq = 0.f;
    for (int i = threadIdx.x; i < cnt; i += 256) {
        const float v = xp[i];
        s += v; sq += v * v;
    }
#pragma unroll
    for (int off = 32; off; off >>= 1) {
        s  += __shfl_xor(s, off);
        sq += __shfl_xor(sq, off);
    }
    __shared__ float rs[4], rq[4], stats[2];
    const int wave = threadIdx.x >> 6, lane = threadIdx.x & 63;
    if (lane == 0) { rs[wave] = s; rq[wave] = sq; }
    __syncthreads();
    if (threadIdx.x == 0) {
        float S = 0.f, Q = 0.f;
        for (int w2 = 0; w2 < 4; ++w2) { S += rs[w2]; Q += rq[w2]; }
        const float mean = S / (float)cnt;
        const float var  = Q / (float)cnt - mean * mean;
        stats[0] = mean;
        stats[1] = rsqrtf(var + 1e-5f);
    }
    __syncthreads();
    const float mean = stats[0], inv = stats[1];
    for (int i = threadIdx.x; i < cnt; i += 256) {
        const int c = i / 49;
        const float v = (xp[i] - mean) * inv * gamma[c] + beta[c];
        xp[i] = fmaxf(v, 0.f);
    }
}

// ---------- global average pool over p ----------
__global__ __launch_bounds__(256) void k_gap(
    const float* __restrict__ x, float* __restrict__ high)
{
    const int idx = blockIdx.x * 256 + threadIdx.x;   // 64*512
    const float* xp = x + idx * 49;
    float s = 0.f;
#pragma unroll
    for (int p = 0; p < 49; ++p) s += xp[p];
    high[idx] = s * (1.f / 49.f);
}

// ---------- roi = relu(actor @ w_fc1^T) ----------
__global__ __launch_bounds__(512) void k_roi(
    const float* __restrict__ actor, const float* __restrict__ wfc1,
    float* __restrict__ roi)
{
    const int n = blockIdx.x;    // 64
    const int h = threadIdx.x;   // 512
    const float* ar = actor + n * CR;
    const float* wr = wfc1 + h * CR;
    float acc = 0.f;
    for (int c = 0; c < CR; ++c)
        acc = fmaf(ar[c], wr[c], acc);
    roi[n * HIDC + h] = fmaxf(acc, 0.f);
}

// ---------- out = concat(roi, high) @ w_fc2^T ----------
__global__ __launch_bounds__(64) void k_final(
    const float* __restrict__ roi, const float* __restrict__ high,
    const float* __restrict__ wfc2, float* __restrict__ out)
{
    const int n = blockIdx.x;    // 64
    const int k = threadIdx.x;   // 64 (60 active)
    if (k >= NCLS) return;
    const float* rr = roi + n * HIDC;
    const float* hh = high + n * HIDC;
    const float* wr = wfc2 + k * (2 * HIDC);
    float acc = 0.f;
    for (int j = 0; j < HIDC; ++j) acc = fmaf(rr[j], wr[j], acc);
    for (int j = 0; j < HIDC; ++j) acc = fmaf(hh[j], wr[HIDC + j], acc);
    out[n * NCLS + k] = acc;
}

// ---------------------------------------------------------------------------
extern "C" void kernel_launch(void* const* d_in, const int* in_sizes, int n_in,
                              void* d_out, int out_size, void* d_ws, size_t ws_size,
                              hipStream_t stream) {
    const float* bg    = (const float*)d_in[0];
    const float* actor = (const float*)d_in[1];
    const float* w1    = (const float*)d_in[2];
    const float* w2    = (const float*)d_in[3];
    const float* wq    = (const float*)d_in[4];
    const float* wk    = (const float*)d_in[5];
    const float* wv    = (const float*)d_in[6];
    const float* wo    = (const float*)d_in[7];
    const float* gamma = (const float*)d_in[8];
    const float* beta  = (const float*)d_in[9];
    const float* wfc1  = (const float*)d_in[10];
    const float* wfc2  = (const float*)d_in[11];
    float* out = (float*)d_out;
    float* ws  = (float*)d_ws;

    const int PLANE = NROI * HIDC * 49;          // 1,605,632
    // workspace layout (floats); total ~16.5M floats (~63 MB)
    float* A    = ws;                            // 131072
    float* B    = A + 131072;                    // 32768
    float* x2   = B + 32768;                     // 64*512*196 = 6,422,528
    float* xA   = x2 + 6422528;                  // PLANE
    float* xB   = xA + PLANE;                    // PLANE
    float* virt = xB + PLANE;                    // PLANE
    float* att  = virt + PLANE;                  // 64*49*64 = 200,704
    float* high = att + 200704;                  // 32768
    float* roi  = high + 32768;                  // 32768
    float* qT   = roi + 32768;                   // PLANE
    float* kT   = qT + PLANE;                    // PLANE
    float* vT   = kT + PLANE;                    // PLANE
    // q,k,v reuse the x2 region after pooling (3*PLANE <= 6,422,528)
    float* q = x2;
    float* k = q + PLANE;
    float* v = k + PLANE;

    const int wlayer = HIDC * HIDC * 9;

    k_Apart<<<512, 256, 0, stream>>>(w1, bg, A);
    k_Bpart<<<64, 512, 0, stream>>>(w1, actor, B);
    k_conv16to14<<<dim3(64, 32), 256, 0, stream>>>(A, B, w2, x2);
    k_pool<<<(PLANE + 255) / 256, 256, 0, stream>>>(x2, xA);

    float* xin = xA;
    float* xout = xB;
    for (int d = 0; d < 2; ++d) {
        k_conv7<<<dim3(64, 8), 256, 0, stream>>>(xin, wq + d * wlayer, nullptr, q);
        k_conv7<<<dim3(64, 8), 256, 0, stream>>>(xin, wk + d * wlayer, nullptr, k);
        k_conv7<<<dim3(64, 8), 256, 0, stream>>>(xin, wv + d * wlayer, nullptr, v);
        k_transpose<<<(PLANE + 255) / 256, 256, 0, stream>>>(q, qT);
        k_transpose<<<(PLANE + 255) / 256, 256, 0, stream>>>(k, kT);
        k_transpose<<<(PLANE + 255) / 256, 256, 0, stream>>>(v, vT);
        k_att<<<dim3(64, 49), 64, 0, stream>>>(qT, kT, att);
        k_virt<<<dim3(64, 49), 256, 0, stream>>>(att, vT, virt);
        k_gn_relu<<<64, 256, 0, stream>>>(virt, gamma + d * HIDC, beta + d * HIDC);
        k_conv7<<<dim3(64, 8), 256, 0, stream>>>(virt, wo + d * wlayer, xin, xout);
        float* t = xin; xin = xout; xout = t;
    }
    // after 2 layers, final features are in xin (== xA)
    k_gap<<<(NROI * HIDC) / 256, 256, 0, stream>>>(xin, high);
    k_roi<<<64, 512, 0, stream>>>(actor, wfc1, roi);
    k_final<<<64, 64, 0, stream>>>(roi, high, wfc2, out);
}

// Round 2
// 1271.048 us; speedup vs baseline: 7.2567x; 7.2567x over previous
//
#include <hip/hip_runtime.h>
#include <math.h>

// ---------------------------------------------------------------------------
// ACARHead — R2: all 9 convs moved to bf16 MFMA implicit GEMM.
// conv1 decomposed (A=bg-part, B=actor-part); conv2 split into 4 quadrant
// convs of the conv7 shape (9x9 window -> 7x7 out) so ONE mfma kernel serves
// conv2 + all 8 hr2o convs. Inputs pre-transposed to [vn][81][512] bf16
// (c-contiguous, zero borders baked), weights to [t][oc][c] bf16.
// ---------------------------------------------------------------------------

typedef __bf16 bf16x8 __attribute__((ext_vector_type(8)));
typedef float  f32x4  __attribute__((ext_vector_type(4)));

#define NROI 64
#define CR   1024
#define HIDC 512
#define NCLS 60
#define PLANE (NROI * HIDC * 49)   // 1,605,632
#define ROWH 40                    // LDS row: 32 data halves + 8 pad (80 B)

// ---------- conv1 decomposition (fp32, tiny) ----------
__global__ __launch_bounds__(256) void k_Apart(
    const float* __restrict__ w1, const float* __restrict__ bg,
    float* __restrict__ A)
{
    const int o = blockIdx.x;      // 512
    const int p = threadIdx.x;     // 256
    const float* wr = w1 + o * (2 * CR);
    float acc = 0.f;
    for (int c = 0; c < CR; ++c)
        acc = fmaf(wr[c], bg[c * 256 + p], acc);
    A[o * 256 + p] = acc;
}

__global__ __launch_bounds__(512) void k_Bpart(
    const float* __restrict__ w1, const float* __restrict__ actor,
    float* __restrict__ B)
{
    const int n = blockIdx.x;      // 64
    const int o = threadIdx.x;     // 512
    const float* ar = actor + n * CR;
    const float* wr = w1 + o * (2 * CR) + CR;
    float acc = 0.f;
    for (int c = 0; c < CR; ++c)
        acc = fmaf(ar[c], wr[c], acc);
    B[n * HIDC + o] = acc;
}

// ---------- weight transpose: [oc][c][9] fp32 -> [t][oc_total][c] bf16 -----
__global__ __launch_bounds__(256) void k_prep_w(
    const float* __restrict__ src, __bf16* __restrict__ dst,
    int oc_base, int oc_total)
{
    const int id = blockIdx.x * 256 + threadIdx.x;  // 512*512
    const int oc = id >> 9, c = id & 511;
    const float* s = src + (size_t)(oc * 512 + c) * 9;
#pragma unroll
    for (int t = 0; t < 9; ++t)
        dst[((size_t)t * oc_total + oc_base + oc) * 512 + c] = (__bf16)s[t];
}

// ---------- input prep: x[n][512][49] fp32 -> inT[n][81][512] bf16, pad=1 --
__global__ __launch_bounds__(256) void k_prep_in7(
    const float* __restrict__ src, __bf16* __restrict__ dst)
{
    const int n = blockIdx.x / 81, sp = blockIdx.x % 81;
    const int r = sp / 9, w = sp % 9;
    const bool inter = (r >= 1 && r <= 7 && w >= 1 && w <= 7);
    const int p = (r - 1) * 7 + (w - 1);
    __bf16* d = dst + ((size_t)n * 81 + sp) * 512;
#pragma unroll
    for (int k = 0; k < 2; ++k) {
        const int c = threadIdx.x + k * 256;
        d[c] = inter ? (__bf16)src[((size_t)n * HIDC + c) * 49 + p] : (__bf16)0.f;
    }
}

// ---------- conv2 input prep: relu(A[c][p]+B[n][c]) -> inT2[vn][81][512] ---
// vn = n*4 + quad; quad (qh,qw) window base (qh*7, qw*7) in the 16x16 plane.
__global__ __launch_bounds__(256) void k_prep_in2(
    const float* __restrict__ A, const float* __restrict__ B,
    __bf16* __restrict__ dst)
{
    const int vn = blockIdx.x / 81, sp = blockIdx.x % 81;
    const int n = vn >> 2, quad = vn & 3;
    const int r = sp / 9, w = sp % 9;
    const int p16 = ((quad >> 1) * 7 + r) * 16 + (quad & 1) * 7 + w;
    __bf16* d = dst + ((size_t)vn * 81 + sp) * 512;
#pragma unroll
    for (int k = 0; k < 2; ++k) {
        const int c = threadIdx.x + k * 256;
        d[c] = (__bf16)fmaxf(A[c * 256 + p16] + B[n * HIDC + c], 0.f);
    }
}

// ---------- unified MFMA conv: 3x3 on a 9x9 plane -> 7x7 out ----------
// wg: 2 vn x 64 oc; 4 waves = (n_local, m_half); wave = 2 Mtiles x 4 Ntiles.
// mode 0: plain, out[vn][oc&511][49] (+conv_id*PLANE for fused qkv)
// mode 1: + residual, out[vn][oc][49]
// mode 2: relu, conv2 quadrants -> out[n][oc][196]
__global__ __launch_bounds__(256, 2) void k_conv_mfma(
    const __bf16* __restrict__ inT,  // [vn][81][512]
    const __bf16* __restrict__ wT,   // [9][oc_total][512]
    const float* __restrict__ resid,
    float* __restrict__ out,
    int oc_total, int mode)
{
    const int tid = threadIdx.x;
    const int wv = tid >> 6, lane = tid & 63;
    const int q = lane >> 4, l16 = lane & 15;
    const int nl = wv >> 1, mh = wv & 1;
    const int g = blockIdx.x;
    const int oc0 = blockIdx.y * 64;

    __shared__ __bf16 s_w[9 * 64 * ROWH];   // 46,080 B
    __shared__ __bf16 s_in[2 * 81 * ROWH];  // 12,960 B

    // A-frag per-lane spatial bases (element index into s_in), 2 Mtiles
    int aBase[2];
#pragma unroll
    for (int mt = 0; mt < 2; ++mt) {
        int p = (mh * 2 + mt) * 16 + l16;
        p = p > 48 ? 48 : p;                 // clamp pad rows (masked at store)
        const int oh = p / 7, ow = p % 7;
        aBase[mt] = (nl * 81 + oh * 9 + ow) * ROWH + q * 8;
    }

    f32x4 acc[2][4];
#pragma unroll
    for (int a = 0; a < 2; ++a)
#pragma unroll
        for (int b = 0; b < 4; ++b) acc[a][b] = (f32x4){0.f, 0.f, 0.f, 0.f};

    const int vnBase = g * 2;
    for (int c0 = 0; c0 < HIDC; c0 += 32) {
        __syncthreads();
        // stage input: 2 vn x 81 rows x 64B (4x16B parts)
        for (int idx = tid; idx < 648; idx += 256) {
            const int ns = idx / 324;
            const int rem = idx - ns * 324;
            const int r = rem >> 2, part = rem & 3;
            const uint4 vv = *(const uint4*)(
                inT + ((size_t)(vnBase + ns) * 81 + r) * 512 + c0 + part * 8);
            *(uint4*)(&s_in[(ns * 81 + r) * ROWH + part * 8]) = vv;
        }
        // stage weights: 9 taps x 64 oc x 64B
        for (int idx = tid; idx < 2304; idx += 256) {
            const int t = idx >> 8;
            const int rem = idx & 255;
            const int r = rem >> 2, part = rem & 3;
            const uint4 vv = *(const uint4*)(
                wT + ((size_t)t * oc_total + oc0 + r) * 512 + c0 + part * 8);
            *(uint4*)(&s_w[(t * 64 + r) * ROWH + part * 8]) = vv;
        }
        __syncthreads();
#pragma unroll
        for (int t = 0; t < 9; ++t) {
            const int tOff = ((t / 3) * 9 + (t % 3)) * ROWH;
            bf16x8 bw[4];
#pragma unroll
            for (int nt = 0; nt < 4; ++nt)
                bw[nt] = *(const bf16x8*)(&s_w[(t * 64 + nt * 16 + l16) * ROWH + q * 8]);
#pragma unroll
            for (int mt = 0; mt < 2; ++mt) {
                const bf16x8 af = *(const bf16x8*)(&s_in[aBase[mt] + tOff]);
#pragma unroll
                for (int nt = 0; nt < 4; ++nt)
                    acc[mt][nt] = __builtin_amdgcn_mfma_f32_16x16x32_bf16(
                        af, bw[nt], acc[mt][nt], 0, 0, 0);
            }
        }
    }

    // epilogue: D row = q*4+r (p within Mtile), col = l16 (oc within Ntile)
    const int vn = vnBase + nl;
#pragma unroll
    for (int mt = 0; mt < 2; ++mt) {
#pragma unroll
        for (int r = 0; r < 4; ++r) {
            const int p = (mh * 2 + mt) * 16 + q * 4 + r;
            if (p >= 49) continue;
#pragma unroll
            for (int nt = 0; nt < 4; ++nt) {
                const int oc = oc0 + nt * 16 + l16;
                const float v = acc[mt][nt][r];
                if (mode == 2) {
                    const int n = vn >> 2, quad = vn & 3;
                    const int oh = p / 7, ow = p % 7;
                    const int addr = (n * HIDC + oc) * 196 +
                                     ((quad >> 1) * 7 + oh) * 14 + (quad & 1) * 7 + ow;
                    out[addr] = fmaxf(v, 0.f);
                } else if (mode == 1) {
                    const int addr = (vn * HIDC + oc) * 49 + p;
                    out[addr] = v + resid[addr];
                } else {
                    const int conv = oc >> 9;
                    const int addr = conv * PLANE + (vn * HIDC + (oc & 511)) * 49 + p;
                    out[addr] = v;
                }
            }
        }
    }
}

// ---------- maxpool 3x3 s2 p1: 14x14 -> 7x7 ----------
__global__ __launch_bounds__(256) void k_pool(
    const float* __restrict__ in, float* __restrict__ out)
{
    const int idx = blockIdx.x * 256 + threadIdx.x;
    if (idx >= NROI * HIDC * 49) return;
    const int j = idx % 7, i = (idx / 7) % 7, nc = idx / 49;
    const float* ip = in + nc * 196;
    float mx = -INFINITY;
#pragma unroll
    for (int di = 0; di < 3; ++di) {
        const int r = 2 * i + di - 1;
        if (r < 0 || r >= 14) continue;
#pragma unroll
        for (int dj = 0; dj < 3; ++dj) {
            const int cj = 2 * j + dj - 1;
            if (cj < 0 || cj >= 14) continue;
            mx = fmaxf(mx, ip[r * 14 + cj]);
        }
    }
    out[idx] = mx;
}

// ---------- transpose [r,c,p] -> [p,r,c] ----------
__global__ __launch_bounds__(256) void k_transpose(
    const float* __restrict__ src, float* __restrict__ dst)
{
    const int idx = blockIdx.x * 256 + threadIdx.x;
    if (idx >= NROI * HIDC * 49) return;
    const int c = idx % HIDC;
    const int r = (idx / HIDC) % NROI;
    const int p = idx / (HIDC * NROI);
    dst[idx] = src[(r * HIDC + c) * 49 + p];
}

// ---------- attention scores + softmax over m ----------
__global__ __launch_bounds__(64) void k_att(
    const float* __restrict__ qT, const float* __restrict__ kT,
    float* __restrict__ att)
{
    const int n = blockIdx.x, p = blockIdx.y;
    const int m = threadIdx.x;
    __shared__ float s_q[HIDC];
    const float* qrow = qT + (p * NROI + n) * HIDC;
    for (int c = m; c < HIDC; c += 64) s_q[c] = qrow[c];
    __syncthreads();
    const float* krow = kT + (p * NROI + m) * HIDC;
    float acc = 0.f;
    for (int c = 0; c < HIDC; ++c)
        acc = fmaf(s_q[c], krow[c], acc);
    acc *= 0.044194173824159216f;
    float mx = acc;
#pragma unroll
    for (int off = 32; off; off >>= 1) mx = fmaxf(mx, __shfl_xor(mx, off));
    const float e = expf(acc - mx);
    float s = e;
#pragma unroll
    for (int off = 32; off; off >>= 1) s += __shfl_xor(s, off);
    att[(n * 49 + p) * 64 + m] = e / s;
}

// ---------- virt[n,c,p] = sum_m att[n,p,m] * vT[p,m,c] ----------
__global__ __launch_bounds__(256) void k_virt(
    const float* __restrict__ att, const float* __restrict__ vT,
    float* __restrict__ virt)
{
    const int n = blockIdx.x, p = blockIdx.y;
    const int tid = threadIdx.x;
    __shared__ float s_a[64];
    if (tid < 64) s_a[tid] = att[(n * 49 + p) * 64 + tid];
    __syncthreads();
    const float* vp = vT + p * NROI * HIDC;
#pragma unroll
    for (int k = 0; k < 2; ++k) {
        const int c = tid + k * 256;
        float acc = 0.f;
        for (int m = 0; m < 64; ++m)
            acc = fmaf(s_a[m], vp[m * HIDC + c], acc);
        virt[(n * HIDC + c) * 49 + p] = acc;
    }
}

// ---------- GroupNorm(1,C) + relu ----------
__global__ __launch_bounds__(256) void k_gn_relu(
    float* __restrict__ x, const float* __restrict__ gamma,
    const float* __restrict__ beta)
{
    const int n = blockIdx.x;
    float* xp = x + n * HIDC * 49;
    const int cnt = HIDC * 49;
    float s = 0.f, sq = 0.f;
    for (int i = threadIdx.x; i < cnt; i += 256) {
        const float v = xp[i];
        s += v; sq += v * v;
    }
#pragma unroll
    for (int off = 32; off; off >>= 1) {
        s  += __shfl_xor(s, off);
        sq += __shfl_xor(sq, off);
    }
    __shared__ float rs[4], rq[4], stats[2];
    const int wave = threadIdx.x >> 6, lane = threadIdx.x & 63;
    if (lane == 0) { rs[wave] = s; rq[wave] = sq; }
    __syncthreads();
    if (threadIdx.x == 0) {
        float S = 0.f, Q = 0.f;
        for (int w2 = 0; w2 < 4; ++w2) { S += rs[w2]; Q += rq[w2]; }
        const float mean = S / (float)cnt;
        const float var  = Q / (float)cnt - mean * mean;
        stats[0] = mean;
        stats[1] = rsqrtf(var + 1e-5f);
    }
    __syncthreads();
    const float mean = stats[0], inv = stats[1];
    for (int i = threadIdx.x; i < cnt; i += 256) {
        const int c = i / 49;
        const float v = (xp[i] - mean) * inv * gamma[c] + beta[c];
        xp[i] = fmaxf(v, 0.f);
    }
}

__global__ __launch_bounds__(256) void k_gap(
    const float* __restrict__ x, float* __restrict__ high)
{
    const int idx = blockIdx.x * 256 + threadIdx.x;
    const float* xp = x + idx * 49;
    float s = 0.f;
#pragma unroll
    for (int p = 0; p < 49; ++p) s += xp[p];
    high[idx] = s * (1.f / 49.f);
}

__global__ __launch_bounds__(512) void k_roi(
    const float* __restrict__ actor, const float* __restrict__ wfc1,
    float* __restrict__ roi)
{
    const int n = blockIdx.x;
    const int h = threadIdx.x;
    const float* ar = actor + n * CR;
    const float* wr = wfc1 + h * CR;
    float acc = 0.f;
    for (int c = 0; c < CR; ++c)
        acc = fmaf(ar[c], wr[c], acc);
    roi[n * HIDC + h] = fmaxf(acc, 0.f);
}

__global__ __launch_bounds__(64) void k_final(
    const float* __restrict__ roi, const float* __restrict__ high,
    const float* __restrict__ wfc2, float* __restrict__ out)
{
    const int n = blockIdx.x;
    const int k = threadIdx.x;
    if (k >= NCLS) return;
    const float* rr = roi + n * HIDC;
    const float* hh = high + n * HIDC;
    const float* wr = wfc2 + k * (2 * HIDC);
    float acc = 0.f;
    for (int j = 0; j < HIDC; ++j) acc = fmaf(rr[j], wr[j], acc);
    for (int j = 0; j < HIDC; ++j) acc = fmaf(hh[j], wr[HIDC + j], acc);
    out[n * NCLS + k] = acc;
}

// ---------------------------------------------------------------------------
extern "C" void kernel_launch(void* const* d_in, const int* in_sizes, int n_in,
                              void* d_out, int out_size, void* d_ws, size_t ws_size,
                              hipStream_t stream) {
    const float* bg    = (const float*)d_in[0];
    const float* actor = (const float*)d_in[1];
    const float* w1    = (const float*)d_in[2];
    const float* w2    = (const float*)d_in[3];
    const float* wq    = (const float*)d_in[4];
    const float* wk    = (const float*)d_in[5];
    const float* wv    = (const float*)d_in[6];
    const float* wo    = (const float*)d_in[7];
    const float* gamma = (const float*)d_in[8];
    const float* beta  = (const float*)d_in[9];
    const float* wfc1  = (const float*)d_in[10];
    const float* wfc2  = (const float*)d_in[11];
    float* out = (float*)d_out;
    float* ws  = (float*)d_ws;

    // ---- fp32 regions ----
    float* A    = ws;                       // 131072
    float* Bp   = A + 131072;               // 32768
    float* x2   = Bp + 32768;               // 6,422,528  (also q,k,v later)
    float* xA   = x2 + 6422528;             // PLANE
    float* xB   = xA + PLANE;
    float* virt = xB + PLANE;
    float* att  = virt + PLANE;             // 200704   } aliased as inT2
    float* high = att + 200704;             // 32768    }
    float* roi  = high + 32768;             // 32768    }
    float* qT   = roi + 32768;              // PLANE    }
    float* kT   = qT + PLANE;               // PLANE    }
    float* vT   = kT + PLANE;               // PLANE    }
    float* padE = vT + PLANE;               // 225280   } -> 5,308,416 floats

    // ---- bf16 regions ----
    __bf16* inT2 = (__bf16*)att;            // 256*81*512 = 10,616,832 halves
    __bf16* inT7 = (__bf16*)(padE + 225280);// 64*81*512  = 2,654,208
    __bf16* wT2  = inT7 + 2654208;          // 9*512*512  = 2,359,296
    __bf16* wTq0 = wT2 + 2359296;           // 9*1536*512 = 7,077,888
    __bf16* wTq1 = wTq0 + 7077888;
    __bf16* wTo0 = wTq1 + 7077888;          // 2,359,296
    __bf16* wTo1 = wTo0 + 2359296;

    float* q = x2;                          // q,k,v reuse x2 after pool
    float* k = q + PLANE;
    float* v = k + PLANE;
    const int WL = HIDC * HIDC * 9;

    k_Apart<<<512, 256, 0, stream>>>(w1, bg, A);
    k_Bpart<<<64, 512, 0, stream>>>(w1, actor, Bp);

    k_prep_w<<<1024, 256, 0, stream>>>(w2, wT2, 0, 512);
    k_prep_w<<<1024, 256, 0, stream>>>(wq,      wTq0, 0,    1536);
    k_prep_w<<<1024, 256, 0, stream>>>(wk,      wTq0, 512,  1536);
    k_prep_w<<<1024, 256, 0, stream>>>(wv,      wTq0, 1024, 1536);
    k_prep_w<<<1024, 256, 0, stream>>>(wq + WL, wTq1, 0,    1536);
    k_prep_w<<<1024, 256, 0, stream>>>(wk + WL, wTq1, 512,  1536);
    k_prep_w<<<1024, 256, 0, stream>>>(wv + WL, wTq1, 1024, 1536);
    k_prep_w<<<1024, 256, 0, stream>>>(wo,      wTo0, 0, 512);
    k_prep_w<<<1024, 256, 0, stream>>>(wo + WL, wTo1, 0, 512);

    k_prep_in2<<<256 * 81, 256, 0, stream>>>(A, Bp, inT2);
    k_conv_mfma<<<dim3(128, 8), 256, 0, stream>>>(inT2, wT2, nullptr, x2, 512, 2);
    k_pool<<<(PLANE + 255) / 256, 256, 0, stream>>>(x2, xA);

    float* xin = xA;
    float* xout = xB;
    for (int d = 0; d < 2; ++d) {
        __bf16* wTq = d ? wTq1 : wTq0;
        __bf16* wTo = d ? wTo1 : wTo0;
        k_prep_in7<<<64 * 81, 256, 0, stream>>>(xin, inT7);
        k_conv_mfma<<<dim3(32, 24), 256, 0, stream>>>(inT7, wTq, nullptr, q, 1536, 0);
        k_transpose<<<(PLANE + 255) / 256, 256, 0, stream>>>(q, qT);
        k_transpose<<<(PLANE + 255) / 256, 256, 0, stream>>>(k, kT);
        k_transpose<<<(PLANE + 255) / 256, 256, 0, stream>>>(v, vT);
        k_att<<<dim3(64, 49), 64, 0, stream>>>(qT, kT, att);
        k_virt<<<dim3(64, 49), 256, 0, stream>>>(att, vT, virt);
        k_gn_relu<<<64, 256, 0, stream>>>(virt, gamma + d * HIDC, beta + d * HIDC);
        k_prep_in7<<<64 * 81, 256, 0, stream>>>(virt, inT7);
        k_conv_mfma<<<dim3(32, 8), 256, 0, stream>>>(inT7, wTo, xin, xout, 512, 1);
        float* t = xin; xin = xout; xout = t;
    }
    k_gap<<<(NROI * HIDC) / 256, 256, 0, stream>>>(xin, high);
    k_roi<<<64, 512, 0, stream>>>(actor, wfc1, roi);
    k_final<<<64, 64, 0, stream>>>(roi, high, wfc2, out);
}

// Round 3
// 794.689 us; speedup vs baseline: 11.6065x; 1.5994x over previous
//
#include <hip/hip_runtime.h>
#include <math.h>

// ---------------------------------------------------------------------------
// ACARHead — R3: MFMA conv with async weight staging (global_load_lds, pre-
// swizzled global layout), VN=4 workgroups, transpose-free attention layouts.
// ---------------------------------------------------------------------------

typedef __bf16 bf16x8 __attribute__((ext_vector_type(8)));
typedef float  f32x4  __attribute__((ext_vector_type(4)));

#define NROI 64
#define CR   1024
#define HIDC 512
#define NCLS 60
#define PLANE (NROI * HIDC * 49)   // 1,605,632
#define ROWH 40                    // s_in row: 32 data halves + 8 pad (80 B)

#if defined(__has_builtin)
#  if __has_builtin(__builtin_amdgcn_global_load_lds)
#    define HAVE_GLL 1
#  endif
#endif

__device__ __forceinline__ void stage16(const void* g, void* lds_base, int lane) {
#ifdef HAVE_GLL
    __builtin_amdgcn_global_load_lds(
        (const __attribute__((address_space(1))) unsigned int*)g,
        (__attribute__((address_space(3))) unsigned int*)lds_base, 16, 0, 0);
#else
    *(uint4*)((char*)lds_base + lane * 16) = *(const uint4*)g;
#endif
}

// ---------- conv1 decomposition (fp32, tiny) ----------
// A_T[p][o] = sum_c w1[o,c] * bg[c,p]
__global__ __launch_bounds__(256) void k_Apart(
    const float* __restrict__ w1, const float* __restrict__ bg,
    float* __restrict__ A_T)
{
    const int o = blockIdx.x;      // 512
    const int p = threadIdx.x;     // 256
    const float* wr = w1 + (size_t)o * (2 * CR);
    float acc = 0.f;
    for (int c = 0; c < CR; ++c)
        acc = fmaf(wr[c], bg[c * 256 + p], acc);
    A_T[p * HIDC + o] = acc;
}

__global__ __launch_bounds__(512) void k_Bpart(
    const float* __restrict__ w1, const float* __restrict__ actor,
    float* __restrict__ B)
{
    const int n = blockIdx.x;      // 64
    const int o = threadIdx.x;     // 512
    const float* ar = actor + n * CR;
    const float* wr = w1 + (size_t)o * (2 * CR) + CR;
    float acc = 0.f;
    for (int c = 0; c < CR; ++c)
        acc = fmaf(ar[c], wr[c], acc);
    B[n * HIDC + o] = acc;
}

// ---------- weight prep: [oc][c][9] fp32 -> swizzled bf16 tiles ----------
// layout: [t][ocblk][chunk16][4096B tile]; within tile row R=oc&63, the 16B
// part is relocated: part' = part ^ ((R&15)>>1 & 3)  (2-way-min bank pattern)
__global__ __launch_bounds__(256) void k_prep_w(
    const float* __restrict__ src, __bf16* __restrict__ dst,
    int OCB, int ocbBase)
{
    const int id = blockIdx.x * 256 + threadIdx.x;  // 512*512
    const int oc = id >> 9, c = id & 511;
    const float* s = src + (size_t)id * 9;
    const int part = (c >> 3) & 3, e = c & 7, chunk = c >> 5;
    const int swz = part ^ ((oc >> 1) & 3);
    const size_t base = ((size_t)(ocbBase + (oc >> 6)) * 16 + chunk) * 2048
                      + (oc & 63) * 32 + swz * 8 + e;
    const size_t tapStride = (size_t)OCB * 16 * 2048;
#pragma unroll
    for (int t = 0; t < 9; ++t)
        dst[t * tapStride + base] = (__bf16)s[t];
}

// ---------- conv2 input: relu(A_T[p][c]+B[n][c]) -> inT2[vn][81][512] -----
__global__ __launch_bounds__(256) void k_prep_in2(
    const float* __restrict__ A_T, const float* __restrict__ B,
    __bf16* __restrict__ dst)
{
    const int vn = blockIdx.x;             // 256
    const int n = vn >> 2, quad = vn & 3;
    const float b0 = B[n * HIDC + threadIdx.x];
    const float b1 = B[n * HIDC + 256 + threadIdx.x];
    for (int sp = 0; sp < 81; ++sp) {
        const int r = sp / 9, w = sp % 9;
        const int p16 = ((quad >> 1) * 7 + r) * 16 + (quad & 1) * 7 + w;
        __bf16* d = dst + ((size_t)vn * 81 + sp) * 512;
        d[threadIdx.x]       = (__bf16)fmaxf(A_T[p16 * HIDC + threadIdx.x] + b0, 0.f);
        d[256 + threadIdx.x] = (__bf16)fmaxf(A_T[p16 * HIDC + 256 + threadIdx.x] + b1, 0.f);
    }
}

// ---------- unified MFMA conv ----------
// VN vn per wg; VN=4: wave w -> vn w, 4 Mt x 4 Nt. VN=2: wave -> (vn w&1, mh w>>1).
// mode 0: qkvT bf16 [p][vn][c] (conv = oc>>9 selects q/k/v plane)
// mode 1: fp32 out[vn][49][512] + resid
// mode 2: bf16 x2 [n][196][512], relu (conv2 quadrants)
template<int VN>
__global__ __launch_bounds__(256, 2) void k_conv_mfma(
    const __bf16* __restrict__ inT,   // [vn][81][512]
    const __bf16* __restrict__ wT,    // swizzled
    int OCB,
    const float* __restrict__ resid,
    float* __restrict__ outf,
    __bf16* __restrict__ outb,
    int mode)
{
    constexpr int MT = (VN == 4) ? 4 : 2;
    const int tid = threadIdx.x;
    const int w = tid >> 6, lane = tid & 63;
    const int q = lane >> 4, l16 = lane & 15;
    const int vn_l = (VN == 4) ? w : (w & 1);
    const int mh   = (VN == 4) ? 0 : (w >> 1);
    const int ocblk = blockIdx.y;
    const int oc0 = ocblk * 64;
    const int vnBase = blockIdx.x * VN;

    __shared__ __align__(16) __bf16 s_w[9 * 64 * 32];        // 36,864 B
    __shared__ __align__(16) __bf16 s_in[VN * 81 * ROWH];

    // per-lane B base (halves): row l16, part q swizzled
    const int bBase = l16 * 32 + ((q ^ ((l16 >> 1) & 3)) << 3);

    int aBase[MT];
#pragma unroll
    for (int mt = 0; mt < MT; ++mt) {
        int p = (mh * MT + mt) * 16 + l16;
        p = p > 48 ? 48 : p;
        const int s = (p / 7) * 9 + (p % 7);
        aBase[mt] = (vn_l * 81 + s) * ROWH + q * 8;
    }

    f32x4 acc[MT][4];
#pragma unroll
    for (int a = 0; a < MT; ++a)
#pragma unroll
        for (int b = 0; b < 4; ++b) acc[a][b] = (f32x4){0.f, 0.f, 0.f, 0.f};

    const size_t tapStride = (size_t)OCB * 16 * 2048;
    for (int ch = 0; ch < 16; ++ch) {
        __syncthreads();
        // --- weights: async copy, 9 x 1024B per wave ---
        const __bf16* wchunk = wT + ((size_t)ocblk * 16 + ch) * 2048 + w * 512 + lane * 8;
#pragma unroll
        for (int t = 0; t < 9; ++t)
            stage16(wchunk + t * tapStride, &s_w[(t * 4 + w) * 512], lane);
        // --- input: ds writes, padded rows ---
        const int c0 = ch * 32;
        for (int idx = tid; idx < VN * 324; idx += 256) {
            const int vnl = idx / 324, rem = idx - vnl * 324;
            const int r = rem >> 2, part = rem & 3;
            const uint4 vv = *(const uint4*)(
                inT + ((size_t)(vnBase + vnl) * 81 + r) * 512 + c0 + part * 8);
            *(uint4*)(&s_in[(vnl * 81 + r) * ROWH + part * 8]) = vv;
        }
        __syncthreads();
#pragma unroll
        for (int t = 0; t < 9; ++t) {
            const int tOffA = ((t / 3) * 9 + (t % 3)) * ROWH;
            bf16x8 bw[4];
#pragma unroll
            for (int nt = 0; nt < 4; ++nt)
                bw[nt] = *(const bf16x8*)(&s_w[(t * 4 + nt) * 512 + bBase]);
#pragma unroll
            for (int mt = 0; mt < MT; ++mt) {
                const bf16x8 af = *(const bf16x8*)(&s_in[aBase[mt] + tOffA]);
#pragma unroll
                for (int nt = 0; nt < 4; ++nt)
                    acc[mt][nt] = __builtin_amdgcn_mfma_f32_16x16x32_bf16(
                        af, bw[nt], acc[mt][nt], 0, 0, 0);
            }
        }
    }

    const int vn = vnBase + vn_l;
#pragma unroll
    for (int mt = 0; mt < MT; ++mt) {
#pragma unroll
        for (int r = 0; r < 4; ++r) {
            const int p = (mh * MT + mt) * 16 + q * 4 + r;
            if (p >= 49) continue;
#pragma unroll
            for (int nt = 0; nt < 4; ++nt) {
                const int oc = oc0 + nt * 16 + l16;
                const float v = acc[mt][nt][r];
                if (mode == 2) {
                    const int n = vn >> 2, quad = vn & 3;
                    const int p14 = ((quad >> 1) * 7 + p / 7) * 14 + (quad & 1) * 7 + p % 7;
                    outb[((size_t)n * 196 + p14) * 512 + oc] = (__bf16)fmaxf(v, 0.f);
                } else if (mode == 1) {
                    const size_t addr = ((size_t)vn * 49 + p) * 512 + oc;
                    outf[addr] = v + resid[addr];
                } else {
                    const int conv = oc >> 9;
                    outb[(size_t)conv * PLANE + ((size_t)p * 64 + vn) * 512 + (oc & 511)]
                        = (__bf16)v;
                }
            }
        }
    }
}

// ---------- fused maxpool(3x3,s2,p1) + bf16 pack + fp32 residual copy -----
__global__ __launch_bounds__(256) void k_pool_prep(
    const __bf16* __restrict__ x2,   // [64][196][512]
    __bf16* __restrict__ inT7,       // [64][81][512]
    float* __restrict__ xA)          // [64][49][512]
{
    const int n = blockIdx.x / 81, sp = blockIdx.x % 81;
    const int r = sp / 9, w = sp % 9;
    __bf16* d = inT7 + ((size_t)n * 81 + sp) * 512;
    if (r < 1 || r > 7 || w < 1 || w > 7) {
        d[threadIdx.x] = (__bf16)0.f; d[256 + threadIdx.x] = (__bf16)0.f;
        return;
    }
    const int i = r - 1, j = w - 1;
#pragma unroll
    for (int k = 0; k < 2; ++k) {
        const int c = threadIdx.x + k * 256;
        float mx = -1e30f;
#pragma unroll
        for (int di = -1; di <= 1; ++di) {
            const int rr = 2 * i + di;
            if (rr < 0 || rr >= 14) continue;
#pragma unroll
            for (int dj = -1; dj <= 1; ++dj) {
                const int cc = 2 * j + dj;
                if (cc < 0 || cc >= 14) continue;
                mx = fmaxf(mx, (float)x2[((size_t)n * 196 + rr * 14 + cc) * 512 + c]);
            }
        }
        d[c] = (__bf16)mx;
        xA[((size_t)n * 49 + i * 7 + j) * 512 + c] = mx;
    }
}

// ---------- plain bf16 pack with zero border: x[n][49][512] -> inT7 ----------
__global__ __launch_bounds__(256) void k_prep_feat(
    const float* __restrict__ x, __bf16* __restrict__ inT7)
{
    const int n = blockIdx.x / 81, sp = blockIdx.x % 81;
    const int r = sp / 9, w = sp % 9;
    __bf16* d = inT7 + ((size_t)n * 81 + sp) * 512;
    const bool inter = (r >= 1 && r <= 7 && w >= 1 && w <= 7);
    const int p = (r - 1) * 7 + (w - 1);
#pragma unroll
    for (int k = 0; k < 2; ++k) {
        const int c = threadIdx.x + k * 256;
        d[c] = inter ? (__bf16)x[((size_t)n * 49 + p) * 512 + c] : (__bf16)0.f;
    }
}

// ---------- GroupNorm(1,C) stats ----------
__global__ __launch_bounds__(256) void k_gn_stats(
    const float* __restrict__ x, float* __restrict__ stats)
{
    const int n = blockIdx.x;
    const float* xp = x + (size_t)n * (HIDC * 49);
    float s = 0.f, sq = 0.f;
    for (int i = threadIdx.x; i < HIDC * 49; i += 256) {
        const float v = xp[i];
        s += v; sq += v * v;
    }
#pragma unroll
    for (int off = 32; off; off >>= 1) {
        s  += __shfl_xor(s, off);
        sq += __shfl_xor(sq, off);
    }
    __shared__ float rs[4], rq[4];
    const int wv = threadIdx.x >> 6, lane = threadIdx.x & 63;
    if (lane == 0) { rs[wv] = s; rq[wv] = sq; }
    __syncthreads();
    if (threadIdx.x == 0) {
        float S = 0.f, Q = 0.f;
        for (int k = 0; k < 4; ++k) { S += rs[k]; Q += rq[k]; }
        const float mean = S / (float)(HIDC * 49);
        const float var  = Q / (float)(HIDC * 49) - mean * mean;
        stats[n * 2]     = mean;
        stats[n * 2 + 1] = rsqrtf(var + 1e-5f);
    }
}

// ---------- fused GN affine + relu + bf16 pack: virt -> inT7 ----------
__global__ __launch_bounds__(256) void k_prep_gn(
    const float* __restrict__ virt, const float* __restrict__ stats,
    const float* __restrict__ gamma, const float* __restrict__ beta,
    __bf16* __restrict__ inT7)
{
    const int n = blockIdx.x / 81, sp = blockIdx.x % 81;
    const int r = sp / 9, w = sp % 9;
    __bf16* d = inT7 + ((size_t)n * 81 + sp) * 512;
    const bool inter = (r >= 1 && r <= 7 && w >= 1 && w <= 7);
    if (!inter) {
        d[threadIdx.x] = (__bf16)0.f; d[256 + threadIdx.x] = (__bf16)0.f;
        return;
    }
    const int p = (r - 1) * 7 + (w - 1);
    const float mean = stats[n * 2], inv = stats[n * 2 + 1];
#pragma unroll
    for (int k = 0; k < 2; ++k) {
        const int c = threadIdx.x + k * 256;
        const float v = virt[((size_t)n * 49 + p) * 512 + c];
        d[c] = (__bf16)fmaxf((v - mean) * inv * gamma[c] + beta[c], 0.f);
    }
}

// ---------- attention scores + softmax over m ----------
__global__ __launch_bounds__(64) void k_att(
    const __bf16* __restrict__ qT,   // [p][n][c] bf16
    const __bf16* __restrict__ kT,
    float* __restrict__ att)
{
    const int n = blockIdx.x, p = blockIdx.y;
    const int m = threadIdx.x;
    __shared__ float s_q[HIDC];
    const __bf16* qrow = qT + ((size_t)p * 64 + n) * HIDC;
    for (int c = m; c < HIDC; c += 64) s_q[c] = (float)qrow[c];
    __syncthreads();
    const __bf16* krow = kT + ((size_t)p * 64 + m) * HIDC;
    float a0 = 0.f, a1 = 0.f, a2 = 0.f, a3 = 0.f;
    for (int c = 0; c < HIDC; c += 4) {
        a0 = fmaf(s_q[c],     (float)krow[c],     a0);
        a1 = fmaf(s_q[c + 1], (float)krow[c + 1], a1);
        a2 = fmaf(s_q[c + 2], (float)krow[c + 2], a2);
        a3 = fmaf(s_q[c + 3], (float)krow[c + 3], a3);
    }
    float acc = (a0 + a1) + (a2 + a3);
    acc *= 0.044194173824159216f;   // 1/sqrt(512)
    float mx = acc;
#pragma unroll
    for (int off = 32; off; off >>= 1) mx = fmaxf(mx, __shfl_xor(mx, off));
    const float e = expf(acc - mx);
    float s = e;
#pragma unroll
    for (int off = 32; off; off >>= 1) s += __shfl_xor(s, off);
    att[((size_t)n * 49 + p) * 64 + m] = e / s;
}

// ---------- virt[n][p][c] = sum_m att[n,p,m] * vT[p][m][c] ----------
__global__ __launch_bounds__(256) void k_virt(
    const float* __restrict__ att, const __bf16* __restrict__ vT,
    float* __restrict__ virt)
{
    const int n = blockIdx.x, p = blockIdx.y;
    __shared__ float s_a[64];
    if (threadIdx.x < 64) s_a[threadIdx.x] = att[((size_t)n * 49 + p) * 64 + threadIdx.x];
    __syncthreads();
#pragma unroll
    for (int k = 0; k < 2; ++k) {
        const int c = threadIdx.x + k * 256;
        float acc = 0.f;
        for (int m = 0; m < 64; ++m)
            acc = fmaf(s_a[m], (float)vT[((size_t)p * 64 + m) * 512 + c], acc);
        virt[((size_t)n * 49 + p) * 512 + c] = acc;
    }
}

// ---------- gap over p ----------
__global__ __launch_bounds__(512) void k_gap(
    const float* __restrict__ x, float* __restrict__ high)
{
    const int n = blockIdx.x, c = threadIdx.x;
    float s = 0.f;
#pragma unroll
    for (int p = 0; p < 49; ++p) s += x[((size_t)n * 49 + p) * 512 + c];
    high[n * HIDC + c] = s * (1.f / 49.f);
}

__global__ __launch_bounds__(512) void k_roi(
    const float* __restrict__ actor, const float* __restrict__ wfc1,
    float* __restrict__ roi)
{
    const int n = blockIdx.x, h = threadIdx.x;
    const float* ar = actor + n * CR;
    const float* wr = wfc1 + (size_t)h * CR;
    float acc = 0.f;
    for (int c = 0; c < CR; ++c)
        acc = fmaf(ar[c], wr[c], acc);
    roi[n * HIDC + h] = fmaxf(acc, 0.f);
}

__global__ __launch_bounds__(64) void k_final(
    const float* __restrict__ roi, const float* __restrict__ high,
    const float* __restrict__ wfc2, float* __restrict__ out)
{
    const int n = blockIdx.x, k = threadIdx.x;
    if (k >= NCLS) return;
    const float* rr = roi + n * HIDC;
    const float* hh = high + n * HIDC;
    const float* wr = wfc2 + (size_t)k * (2 * HIDC);
    float acc = 0.f;
    for (int j = 0; j < HIDC; ++j) acc = fmaf(rr[j], wr[j], acc);
    for (int j = 0; j < HIDC; ++j) acc = fmaf(hh[j], wr[HIDC + j], acc);
    out[n * NCLS + k] = acc;
}

// ---------------------------------------------------------------------------
extern "C" void kernel_launch(void* const* d_in, const int* in_sizes, int n_in,
                              void* d_out, int out_size, void* d_ws, size_t ws_size,
                              hipStream_t stream) {
    const float* bg    = (const float*)d_in[0];
    const float* actor = (const float*)d_in[1];
    const float* w1    = (const float*)d_in[2];
    const float* w2    = (const float*)d_in[3];
    const float* wq    = (const float*)d_in[4];
    const float* wk    = (const float*)d_in[5];
    const float* wv    = (const float*)d_in[6];
    const float* wo    = (const float*)d_in[7];
    const float* gamma = (const float*)d_in[8];
    const float* beta  = (const float*)d_in[9];
    const float* wfc1  = (const float*)d_in[10];
    const float* wfc2  = (const float*)d_in[11];
    float* out = (float*)d_out;
    float* ws  = (float*)d_ws;

    // ---- fp32 regions ----
    float* A_T   = ws;                        // 131,072
    float* Bp    = A_T + 131072;              // 32,768
    float* xA    = Bp + 32768;                // PLANE
    float* xB    = xA + PLANE;                // PLANE
    float* virt  = xB + PLANE;                // PLANE
    float* att   = virt + PLANE;              // 200,704
    float* stats = att + 200704;              // 128
    float* high  = stats + 128;               // 32,768
    float* roi   = high + 32768;              // 32,768
    float* fend  = roi + 32768;
    // ---- bf16 regions ----
    __bf16* x2   = (__bf16*)fend;             // 64*196*512 = 6,422,528
    __bf16* inT2 = x2 + 6422528;              // 256*81*512 = 10,616,832
    __bf16* inT7 = inT2 + 10616832;           // 64*81*512  = 2,654,208
    __bf16* qkvT = inT7 + 2654208;            // 3*PLANE    = 4,816,896
    __bf16* wTs  = qkvT + 4816896;            // 9*1536*512 = 7,077,888 (reused)

    const int WL = HIDC * HIDC * 9;

    k_Apart<<<512, 256, 0, stream>>>(w1, bg, A_T);
    k_Bpart<<<64, 512, 0, stream>>>(w1, actor, Bp);
    k_prep_in2<<<256, 256, 0, stream>>>(A_T, Bp, inT2);

    // conv2 (VN=4 over 256 quadrant-planes)
    k_prep_w<<<1024, 256, 0, stream>>>(w2, wTs, 8, 0);
    k_conv_mfma<4><<<dim3(64, 8), 256, 0, stream>>>(
        inT2, wTs, 8, nullptr, nullptr, x2, 2);
    k_pool_prep<<<64 * 81, 256, 0, stream>>>(x2, inT7, xA);

    float* xin = xA;
    float* xout = xB;
    for (int d = 0; d < 2; ++d) {
        if (d > 0)
            k_prep_feat<<<64 * 81, 256, 0, stream>>>(xin, inT7);
        // fused qkv conv -> qT/kT/vT bf16 [p][n][c]
        k_prep_w<<<1024, 256, 0, stream>>>(wq + d * WL, wTs, 24, 0);
        k_prep_w<<<1024, 256, 0, stream>>>(wk + d * WL, wTs, 24, 8);
        k_prep_w<<<1024, 256, 0, stream>>>(wv + d * WL, wTs, 24, 16);
        k_conv_mfma<4><<<dim3(16, 24), 256, 0, stream>>>(
            inT7, wTs, 24, nullptr, nullptr, qkvT, 0);
        k_att<<<dim3(64, 49), 64, 0, stream>>>(qkvT, qkvT + PLANE, att);
        k_virt<<<dim3(64, 49), 256, 0, stream>>>(att, qkvT + 2 * PLANE, virt);
        k_gn_stats<<<64, 256, 0, stream>>>(virt, stats);
        k_prep_gn<<<64 * 81, 256, 0, stream>>>(virt, stats,
                                               gamma + d * HIDC, beta + d * HIDC, inT7);
        // wo conv + residual (VN=2 -> 256 wgs, 1/CU across full chip)
        k_prep_w<<<1024, 256, 0, stream>>>(wo + d * WL, wTs, 8, 0);
        k_conv_mfma<2><<<dim3(32, 8), 256, 0, stream>>>(
            inT7, wTs, 8, xin, xout, nullptr, 1);
        float* t = xin; xin = xout; xout = t;
    }
    k_gap<<<64, 512, 0, stream>>>(xin, high);
    k_roi<<<64, 512, 0, stream>>>(actor, wfc1, roi);
    k_final<<<64, 64, 0, stream>>>(roi, high, wfc2, out);
}